// Round 6
// baseline (39.923 us; speedup 1.0000x reference)
//
#include <hip/hip_runtime.h>
#include <hip/hip_bf16.h>
#include <math.h>

// inputs: [B=64, I=2048, P=16] f32
// W:      [I=2048, J=32, P=16, D=32] f32
// bias:   [1, I, J, 1, 1] f32
// out:    [B=64, J=32, D=32] f32
#define I_CAP 2048
#define P_DIM 16
#define J_CAP 32
#define D_DIM 32
#define B_SZ  64
#define KCN   32            // i-chunks; grid = KCN * 16 j-pairs = 512 blocks
#define IPB   (I_CAP / KCN) // 64 i per block
#define IPW   (IPB / 4)     // 16 i per wave

typedef __attribute__((ext_vector_type(8)))  short short8_t;
typedef __attribute__((ext_vector_type(16))) float f32x16;

__device__ __forceinline__ short f2bf(float f) {
    __hip_bfloat16 h = __float2bfloat16(f);   // RNE
    return __builtin_bit_cast(short, h);
}

// ---------------- k1: fused softmax + main GEMM via bf16 MFMA ----------------
// Logical block (kc, jp): 4 waves on disjoint i-subranges, each wave computes
// j0=2*jp and j1=2*jp+1 (4 KB contiguous W per round, 4 MFMA per round).
// Softmax over j of bias for this block's 64 i's is recomputed per block into
// LDS (bias is 256 KB total, L2-hot; 16x redundancy is ~free).
// XCD-chunked bid swizzle: xcd = bid&7 owns 64 consecutive logical blocks =
// 4 kc groups x 16 jp -> the 16 sharers of each 256KB A-slice are co-XCD (L2-hot).
// B-frag: lane l -> n=d=(l&31), k=p=(l>>5)*8+e   (k-permutation-safe: A uses same map)
// A-frag: lane l -> m=b=(l&31)+32*mf, k=p=(l>>5)*8+e  -> 8 consecutive fp32
// C/D:    b = mf*32 + (reg&3) + 8*(reg>>2) + 4*(l>>5), d = l&31   [m74/m101]
__global__ __launch_bounds__(256, 2) void caps_main_k(const float* __restrict__ inputs,
                                                      const float* __restrict__ W,
                                                      const float* __restrict__ bias,
                                                      float* __restrict__ partial) {
    __shared__ float red[4 * 4096];   // 64 KB: [wave][j-pair][64 b][32 d]
    __shared__ float c_lds[64][2];    // c[i_local][j0/j1]
    const int t  = threadIdx.x;
    const int l  = t & 63;
    const int wv = t >> 6;

    // chunked XCD swizzle (bijective: 512 % 8 == 0)
    const int orig = blockIdx.x;
    const int wgid = (orig & 7) * 64 + (orig >> 3);
    const int kc = wgid >> 4;          // 0..31
    const int jp = wgid & 15;          // 0..15
    const int j0 = jp * 2;

    const int g  = l >> 5;     // p-half selector (k-group)
    const int dn = l & 31;     // d for B-frag, b for A-frag

    const int i0blk = kc * IPB;
    const int i0    = i0blk + wv * IPW;

    // ---- fused softmax: c[i, j] = softmax_j(bias[i, :]) for this block's i's ----
    {
        const int jj = t & 31;          // j
        const int ib = t >> 5;          // 0..7
#pragma unroll
        for (int pass = 0; pass < 8; ++pass) {
            const int ii = pass * 8 + ib;
            float x = bias[(i0blk + ii) * J_CAP + jj];
            float m = x;
#pragma unroll
            for (int k = 16; k >= 1; k >>= 1) m = fmaxf(m, __shfl_xor(m, k));
            float e = expf(x - m);
            float s = e;
#pragma unroll
            for (int k = 16; k >= 1; k >>= 1) s += __shfl_xor(s, k);
            float cv = e / s;
            if (jj == j0)     c_lds[ii][0] = cv;
            if (jj == j0 + 1) c_lds[ii][1] = cv;
        }
    }
    __syncthreads();

    const float* wlane  = W + (((size_t)(i0 * J_CAP + j0)) << 9) + g * 256 + dn;
    const float* alane0 = inputs + ((size_t)dn << 15) + (size_t)i0 * 16 + g * 8;
    const float* alane1 = alane0 + ((size_t)32 << 15);

    f32x16 accA0 = {};   // j0, b 0..31
    f32x16 accA1 = {};   // j0, b 32..63
    f32x16 accB0 = {};   // j1, b 0..31
    f32x16 accB1 = {};   // j1, b 32..63

#pragma unroll 4
    for (int r = 0; r < IPW; ++r) {
        const float cj0 = c_lds[wv * IPW + r][0];
        const float cj1 = c_lds[wv * IPW + r][1];
        float w0buf[8], w1buf[8];
#pragma unroll
        for (int e = 0; e < 8; ++e) {
            w0buf[e] = wlane[(size_t)r * 16384 + e * 32];        // j0 rows
            w1buf[e] = wlane[(size_t)r * 16384 + 512 + e * 32];  // j1 rows (adjacent 2KB)
        }
        float4 a0 = *(const float4*)(alane0 + r * 16);
        float4 a1 = *(const float4*)(alane0 + r * 16 + 4);
        float4 a2 = *(const float4*)(alane1 + r * 16);
        float4 a3 = *(const float4*)(alane1 + r * 16 + 4);

        short8_t bf0, bf1, af0, af1;
#pragma unroll
        for (int e = 0; e < 8; ++e) bf0[e] = f2bf(w0buf[e] * cj0);
#pragma unroll
        for (int e = 0; e < 8; ++e) bf1[e] = f2bf(w1buf[e] * cj1);
        af0[0] = f2bf(a0.x); af0[1] = f2bf(a0.y); af0[2] = f2bf(a0.z); af0[3] = f2bf(a0.w);
        af0[4] = f2bf(a1.x); af0[5] = f2bf(a1.y); af0[6] = f2bf(a1.z); af0[7] = f2bf(a1.w);
        af1[0] = f2bf(a2.x); af1[1] = f2bf(a2.y); af1[2] = f2bf(a2.z); af1[3] = f2bf(a2.w);
        af1[4] = f2bf(a3.x); af1[5] = f2bf(a3.y); af1[6] = f2bf(a3.z); af1[7] = f2bf(a3.w);

        accA0 = __builtin_amdgcn_mfma_f32_32x32x16_bf16(af0, bf0, accA0, 0, 0, 0);
        accA1 = __builtin_amdgcn_mfma_f32_32x32x16_bf16(af1, bf0, accA1, 0, 0, 0);
        accB0 = __builtin_amdgcn_mfma_f32_32x32x16_bf16(af0, bf1, accB0, 0, 0, 0);
        accB1 = __builtin_amdgcn_mfma_f32_32x32x16_bf16(af1, bf1, accB1, 0, 0, 0);
    }

    // ---- epilogue: per-wave C -> LDS (conflict-free), 4-wave sum, partial write --
    {
        float* rw = red + wv * 4096;
#pragma unroll
        for (int reg = 0; reg < 16; ++reg) {
            const int b0 = (reg & 3) + 8 * (reg >> 2) + 4 * g;
            rw[b0 * 32 + dn]               = accA0[reg];
            rw[(b0 + 32) * 32 + dn]        = accA1[reg];
            rw[2048 + b0 * 32 + dn]        = accB0[reg];
            rw[2048 + (b0 + 32) * 32 + dn] = accB1[reg];
        }
    }
    __syncthreads();
    {
        float* dstbase = partial + (size_t)(kc * J_CAP + j0) * 2048;
#pragma unroll
        for (int jj = 0; jj < 2; ++jj) {
#pragma unroll
            for (int s = 0; s < 2; ++s) {
                const int o = jj * 2048 + s * 1024 + t * 4;
                float4 v0 = *(const float4*)(red + o);
                float4 v1 = *(const float4*)(red + 4096 + o);
                float4 v2 = *(const float4*)(red + 8192 + o);
                float4 v3 = *(const float4*)(red + 12288 + o);
                float4 sum = {v0.x + v1.x + v2.x + v3.x,
                              v0.y + v1.y + v2.y + v3.y,
                              v0.z + v1.z + v2.z + v3.z,
                              v0.w + v1.w + v2.w + v3.w};
                *(float4*)(dstbase + o) = sum;   // partial[(kc*32 + j0+jj)*2048 + ...]
            }
        }
    }
}

// ---------------- k2: reduce KCN partials + squash (vectorized) ----------------
// 128 blocks x 256 thr = 32768 threads. tid2 -> row = tid2>>4 (j = row>>6,
// b = row&63), d4 = (tid2>>1)&7, half = tid2&1 (kc half). Each thread sums 16
// kc's as float4, pair-combines via shfl_xor(1), row-squash via shfl 2/4/8.
__global__ __launch_bounds__(256) void caps_reduce_squash_k(const float* __restrict__ partial,
                                                            float* __restrict__ out) {
    const int tid2 = blockIdx.x * 256 + threadIdx.x;
    const int row  = tid2 >> 4;
    const int sub  = tid2 & 15;
    const int d4   = sub >> 1;
    const int half = sub & 1;
    const int j = row >> 6, b = row & 63;

    const float* src = partial + ((size_t)(half * 16) * J_CAP + j) * 2048 + b * 32 + d4 * 4;
    float4 v = {0.f, 0.f, 0.f, 0.f};
#pragma unroll
    for (int kc = 0; kc < 16; ++kc) {
        float4 p = *(const float4*)(src + (size_t)kc * J_CAP * 2048);
        v.x += p.x; v.y += p.y; v.z += p.z; v.w += p.w;
    }
    // combine the two kc-halves (lane pair differs only in `half`)
    v.x += __shfl_xor(v.x, 1); v.y += __shfl_xor(v.y, 1);
    v.z += __shfl_xor(v.z, 1); v.w += __shfl_xor(v.w, 1);

    float sq = v.x * v.x + v.y * v.y + v.z * v.z + v.w * v.w;
#pragma unroll
    for (int m = 2; m <= 8; m <<= 1) sq += __shfl_xor(sq, m);
    // scale = s2 / (1+s2) / sqrt(s2)  (exactly as reference)
    float scale = sq / (1.0f + sq) / sqrtf(sq);
    if (half == 0) {
        float4 o = {v.x * scale, v.y * scale, v.z * scale, v.w * scale};
        *(float4*)(out + (size_t)b * (J_CAP * D_DIM) + j * D_DIM + d4 * 4) = o;
    }
}

extern "C" void kernel_launch(void* const* d_in, const int* in_sizes, int n_in,
                              void* d_out, int out_size, void* d_ws, size_t ws_size,
                              hipStream_t stream) {
    const float* inputs = (const float*)d_in[0];
    const float* W      = (const float*)d_in[1];
    const float* bias   = (const float*)d_in[2];
    float* out = (float*)d_out;

    float* partial = (float*)d_ws;   // 32*32*2048 f32 = 8 MB

    caps_main_k<<<dim3(KCN * 16), dim3(256), 0, stream>>>(inputs, W, bias, partial);
    caps_reduce_squash_k<<<dim3(128), dim3(256), 0, stream>>>(partial, out);
}

// Round 7
// 35.415 us; speedup vs baseline: 1.1273x; 1.1273x over previous
//
#include <hip/hip_runtime.h>
#include <hip/hip_bf16.h>
#include <math.h>

// inputs: [B=64, I=2048, P=16] f32
// W:      [I=2048, J=32, P=16, D=32] f32
// bias:   [1, I, J, 1, 1] f32
// out:    [B=64, J=32, D=32] f32
#define I_CAP 2048
#define P_DIM 16
#define J_CAP 32
#define D_DIM 32
#define B_SZ  64
#define KCN   32            // i-chunks; partial = KCN*32*2048 f32 = 8 MB
#define IPB   (I_CAP / KCN) // 64 i per block
#define NWAVE 8
#define IPW   (IPB / NWAVE) // 8 i per wave

typedef __attribute__((ext_vector_type(8)))  short short8_t;
typedef __attribute__((ext_vector_type(16))) float f32x16;

__device__ __forceinline__ short f2bf(float f) {
    __hip_bfloat16 h = __float2bfloat16(f);   // RNE
    return __builtin_bit_cast(short, h);
}

// ---------------- k1: fused softmax + main GEMM via bf16 MFMA ----------------
// Logical block (kc, jq): 512 thr = 8 waves on disjoint i-subranges (8 i each);
// every wave computes the same 4 j's (j0..j0+3): per-(wave,i) W read = 8 KB
// CONTIGUOUS (vs 4 KB in R5/R6) -> better DRAM burst locality; A dwordx4 loads
// amortized over 8 MFMA/round. grid = 32 kc x 8 jq = 256 = 1 block/CU,
// 8 waves/CU = 2/SIMD (same occupancy as R5). KCN=32 keeps partial at 8 MB.
// XCD-chunked bid swizzle: xcd owns 32 blocks = 4 kc x 8 jq -> all 8 sharers
// of each A-slice co-XCD; W region per XCD = 16 MB contiguous.
// B-frag: lane l -> n=d=(l&31), k=p=(l>>5)*8+e   (k-permutation-safe: A uses same map)
// A-frag: lane l -> m=b=(l&31)+32*mf, k=p=(l>>5)*8+e  -> 8 consecutive fp32
// C/D:    b = mf*32 + (reg&3) + 8*(reg>>2) + 4*(l>>5), d = l&31   [m74/m101]
__global__ __launch_bounds__(512, 2) void caps_main_k(const float* __restrict__ inputs,
                                                      const float* __restrict__ W,
                                                      const float* __restrict__ bias,
                                                      float* __restrict__ partial) {
    __shared__ float red[NWAVE * 2048];   // 64 KB
    __shared__ float c_lds[IPB][4];       // c[i_local][j0..j0+3]
    const int t  = threadIdx.x;
    const int l  = t & 63;
    const int wv = t >> 6;                // 0..7

    // chunked XCD swizzle (bijective: 256 % 8 == 0)
    const int orig = blockIdx.x;
    const int wgid = (orig & 7) * 32 + (orig >> 3);
    const int kc = wgid >> 3;             // 0..31
    const int jq = wgid & 7;              // 0..7
    const int j0 = jq * 4;

    const int g  = l >> 5;     // p-half selector (k-group)
    const int dn = l & 31;     // d for B-frag, b for A-frag

    const int i0blk = kc * IPB;
    const int i0    = i0blk + wv * IPW;

    // ---- fused softmax: c[i, j0..j0+3] for this block's 64 i's ----
    {
        const int jj = t & 31;            // j
        const int ib = t >> 5;            // 0..15
        const int jr = jj - j0;
#pragma unroll
        for (int pass = 0; pass < 4; ++pass) {
            const int ii = pass * 16 + ib;
            float x = bias[(i0blk + ii) * J_CAP + jj];
            float m = x;
#pragma unroll
            for (int k = 16; k >= 1; k >>= 1) m = fmaxf(m, __shfl_xor(m, k));
            float e = expf(x - m);
            float s = e;
#pragma unroll
            for (int k = 16; k >= 1; k >>= 1) s += __shfl_xor(s, k);
            if ((unsigned)jr < 4u) c_lds[ii][jr] = e / s;
        }
    }
    __syncthreads();

    const float* wlane  = W + (((size_t)(i0 * J_CAP + j0)) << 9) + g * 256 + dn;
    const float* alane0 = inputs + ((size_t)dn << 15) + (size_t)i0 * 16 + g * 8;
    const float* alane1 = alane0 + ((size_t)32 << 15);

    f32x16 acc[4][2];   // [jj][b-half]
#pragma unroll
    for (int jj = 0; jj < 4; ++jj) { acc[jj][0] = (f32x16){}; acc[jj][1] = (f32x16){}; }

#pragma unroll 2
    for (int r = 0; r < IPW; ++r) {
        // W: 8 KB contiguous per (wave, i): j0..j0+3, each 2 KB
        float wb[4][8];
#pragma unroll
        for (int jj = 0; jj < 4; ++jj)
#pragma unroll
            for (int e = 0; e < 8; ++e)
                wb[jj][e] = wlane[(size_t)r * 16384 + jj * 512 + e * 32];

        float4 a0 = *(const float4*)(alane0 + r * 16);
        float4 a1 = *(const float4*)(alane0 + r * 16 + 4);
        float4 a2 = *(const float4*)(alane1 + r * 16);
        float4 a3 = *(const float4*)(alane1 + r * 16 + 4);

        short8_t af0, af1;
        af0[0] = f2bf(a0.x); af0[1] = f2bf(a0.y); af0[2] = f2bf(a0.z); af0[3] = f2bf(a0.w);
        af0[4] = f2bf(a1.x); af0[5] = f2bf(a1.y); af0[6] = f2bf(a1.z); af0[7] = f2bf(a1.w);
        af1[0] = f2bf(a2.x); af1[1] = f2bf(a2.y); af1[2] = f2bf(a2.z); af1[3] = f2bf(a2.w);
        af1[4] = f2bf(a3.x); af1[5] = f2bf(a3.y); af1[6] = f2bf(a3.z); af1[7] = f2bf(a3.w);

#pragma unroll
        for (int jj = 0; jj < 4; ++jj) {
            const float cj = c_lds[wv * IPW + r][jj];
            short8_t bf;
#pragma unroll
            for (int e = 0; e < 8; ++e) bf[e] = f2bf(wb[jj][e] * cj);
            acc[jj][0] = __builtin_amdgcn_mfma_f32_32x32x16_bf16(af0, bf, acc[jj][0], 0, 0, 0);
            acc[jj][1] = __builtin_amdgcn_mfma_f32_32x32x16_bf16(af1, bf, acc[jj][1], 0, 0, 0);
        }
    }

    // ---- epilogue: 4 passes (one per jj): 8-wave LDS reduce -> partial ----
#pragma unroll
    for (int jj = 0; jj < 4; ++jj) {
        __syncthreads();   // red free (prev pass read / softmax done)
        {
            float* rw = red + wv * 2048;
#pragma unroll
            for (int reg = 0; reg < 16; ++reg) {
                const int b0 = (reg & 3) + 8 * (reg >> 2) + 4 * g;
                rw[b0 * 32 + dn]        = acc[jj][0][reg];
                rw[(b0 + 32) * 32 + dn] = acc[jj][1][reg];
            }
        }
        __syncthreads();
        {
            const int o = t * 4;   // 512 thr x 4 floats = 2048
            float4 v = {0.f, 0.f, 0.f, 0.f};
#pragma unroll
            for (int w8 = 0; w8 < NWAVE; ++w8) {
                float4 p = *(const float4*)(red + w8 * 2048 + o);
                v.x += p.x; v.y += p.y; v.z += p.z; v.w += p.w;
            }
            *(float4*)(partial + (size_t)(kc * J_CAP + j0 + jj) * 2048 + o) = v;
        }
    }
}

// ---------------- k2: reduce KCN partials + squash (vectorized) ----------------
// 128 blocks x 256 thr = 32768 threads. tid2 -> row = tid2>>4 (j = row>>6,
// b = row&63), d4 = (tid2>>1)&7, half = tid2&1 (kc half). Each thread sums 16
// kc's as float4, pair-combines via shfl_xor(1), row-squash via shfl 2/4/8.
__global__ __launch_bounds__(256) void caps_reduce_squash_k(const float* __restrict__ partial,
                                                            float* __restrict__ out) {
    const int tid2 = blockIdx.x * 256 + threadIdx.x;
    const int row  = tid2 >> 4;
    const int sub  = tid2 & 15;
    const int d4   = sub >> 1;
    const int half = sub & 1;
    const int j = row >> 6, b = row & 63;

    const float* src = partial + ((size_t)(half * 16) * J_CAP + j) * 2048 + b * 32 + d4 * 4;
    float4 v = {0.f, 0.f, 0.f, 0.f};
#pragma unroll
    for (int kc = 0; kc < 16; ++kc) {
        float4 p = *(const float4*)(src + (size_t)kc * J_CAP * 2048);
        v.x += p.x; v.y += p.y; v.z += p.z; v.w += p.w;
    }
    // combine the two kc-halves (lane pair differs only in `half`)
    v.x += __shfl_xor(v.x, 1); v.y += __shfl_xor(v.y, 1);
    v.z += __shfl_xor(v.z, 1); v.w += __shfl_xor(v.w, 1);

    float sq = v.x * v.x + v.y * v.y + v.z * v.z + v.w * v.w;
#pragma unroll
    for (int m = 2; m <= 8; m <<= 1) sq += __shfl_xor(sq, m);
    // scale = s2 / (1+s2) / sqrt(s2)  (exactly as reference)
    float scale = sq / (1.0f + sq) / sqrtf(sq);
    if (half == 0) {
        float4 o = {v.x * scale, v.y * scale, v.z * scale, v.w * scale};
        *(float4*)(out + (size_t)b * (J_CAP * D_DIM) + j * D_DIM + d4 * 4) = o;
    }
}

extern "C" void kernel_launch(void* const* d_in, const int* in_sizes, int n_in,
                              void* d_out, int out_size, void* d_ws, size_t ws_size,
                              hipStream_t stream) {
    const float* inputs = (const float*)d_in[0];
    const float* W      = (const float*)d_in[1];
    const float* bias   = (const float*)d_in[2];
    float* out = (float*)d_out;

    float* partial = (float*)d_ws;   // 32*32*2048 f32 = 8 MB

    caps_main_k<<<dim3(KCN * 8), dim3(512), 0, stream>>>(inputs, W, bias, partial);
    caps_reduce_squash_k<<<dim3(128), dim3(256), 0, stream>>>(partial, out);
}

// Round 8
// 35.315 us; speedup vs baseline: 1.1305x; 1.0028x over previous
//
#include <hip/hip_runtime.h>
#include <hip/hip_bf16.h>
#include <math.h>

// inputs: [B=64, I=2048, P=16] f32
// W:      [I=2048, J=32, P=16, D=32] f32
// bias:   [1, I, J, 1, 1] f32
// out:    [B=64, J=32, D=32] f32
#define I_CAP 2048
#define P_DIM 16
#define J_CAP 32
#define D_DIM 32
#define B_SZ  64
#define KCN   32            // i-chunks; partial = KCN*32*2048 f32 = 8 MB
#define IPB   (I_CAP / KCN) // 64 i per block
#define NWAVE 8
#define IPW   (IPB / NWAVE) // 8 i per wave

typedef __attribute__((ext_vector_type(8)))  short short8_t;
typedef __attribute__((ext_vector_type(16))) float f32x16;

__device__ __forceinline__ short f2bf(float f) {
    __hip_bfloat16 h = __float2bfloat16(f);   // RNE
    return __builtin_bit_cast(short, h);
}

// async global->LDS, 16B per lane; LDS dest = uniform base + lane*16 (linear);
// global src is per-lane.
#define GLOAD_LDS16(gp, lp)                                                     \
    __builtin_amdgcn_global_load_lds(                                           \
        (const __attribute__((address_space(1))) void*)(gp),                    \
        (__attribute__((address_space(3))) void*)(lp), 16, 0, 0)

// ---------------- k1: fused softmax + main GEMM via bf16 MFMA ----------------
// Geometry as R7 (proven): block (kc, jq) = 512 thr = 8 waves on disjoint 8-i
// subranges, each wave computes j0..j0+3 for all 64 b; per-(wave,i) W read =
// 8 KB contiguous. grid = 32 kc x 8 jq = 256 = 1 block/CU (LDS-enforced).
// XCD-chunked bid swizzle keeps A-slice sharers co-XCD.
// NEW (R8): W staged via per-wave double-buffered global_load_lds (8 x 16B-wide
// DMA per round) with counted s_waitcnt vmcnt(12) -- next round's 8 W-DMAs +
// 4 A-loads stay in flight across the whole compute phase (never drain to 0
// until the tail). sched_barrier(0) fences per rule 18/21. A operand stays as
// 2-deep register prefetch (L2-hot, compiler-managed wait == manual count).
// LDS: 8 waves x 2 bufs x 8 KB = 128 KB, reused as the 64 KB reduce scratch in
// the epilogue (each wave's red region == its own buf0; barrier before x-read).
// B-frag: lane l -> n=d=(l&31), k=p=(l>>5)*8+e   (k-permutation-safe: A uses same map)
// A-frag: lane l -> m=b=(l&31)+32*mf, k=p=(l>>5)*8+e  -> 8 consecutive fp32
// C/D:    b = mf*32 + (reg&3) + 8*(reg>>2) + 4*(l>>5), d = l&31   [m74/m101]
__global__ __launch_bounds__(512, 2) void caps_main_k(const float* __restrict__ inputs,
                                                      const float* __restrict__ W,
                                                      const float* __restrict__ bias,
                                                      float* __restrict__ partial) {
    __shared__ float lds[33024];        // 129 KB: [0,32768) W dbuf / red; [32768,33024) c
    float* c_lds = lds + 32768;         // c[i_local*4 + jr]
    const int t  = threadIdx.x;
    const int l  = t & 63;
    const int wv = t >> 6;              // 0..7

    // chunked XCD swizzle (bijective: 256 % 8 == 0)
    const int orig = blockIdx.x;
    const int wgid = (orig & 7) * 32 + (orig >> 3);
    const int kc = wgid >> 3;           // 0..31
    const int jq = wgid & 7;            // 0..7
    const int j0 = jq * 4;

    const int g  = l >> 5;     // p-half selector (k-group)
    const int dn = l & 31;     // d for B-frag, b for A-frag

    const int i0blk = kc * IPB;
    const int i0    = i0blk + wv * IPW;

    float* wbuf = lds + wv * 4096;      // this wave's 2 x 2048-float W buffers

    // per-lane W source base (chunk = [j0..j0+3][16p][32d] = 2048 floats per i)
    const float* wsrc   = W + (((size_t)(i0 * J_CAP + j0)) << 9) + l * 4;
    const float* alane0 = inputs + ((size_t)dn << 15) + (size_t)i0 * 16 + g * 8;
    const float* alane1 = alane0 + ((size_t)32 << 15);

    // ---- prologue: stage round 0 (flies under the softmax) ----
    float4 aP[2][4];
#pragma unroll
    for (int n = 0; n < 8; ++n)
        GLOAD_LDS16(wsrc + n * 256, wbuf + n * 256);
    aP[0][0] = *(const float4*)(alane0);
    aP[0][1] = *(const float4*)(alane0 + 4);
    aP[0][2] = *(const float4*)(alane1);
    aP[0][3] = *(const float4*)(alane1 + 4);

    // ---- fused softmax: c[i, j0..j0+3] for this block's 64 i's ----
    {
        const int jj = t & 31;          // j
        const int ib = t >> 5;          // 0..15
        const int jr = jj - j0;
#pragma unroll
        for (int pass = 0; pass < 4; ++pass) {
            const int ii = pass * 16 + ib;
            float x = bias[(i0blk + ii) * J_CAP + jj];
            float m = x;
#pragma unroll
            for (int k = 16; k >= 1; k >>= 1) m = fmaxf(m, __shfl_xor(m, k));
            float e = expf(x - m);
            float s = e;
#pragma unroll
            for (int k = 16; k >= 1; k >>= 1) s += __shfl_xor(s, k);
            if ((unsigned)jr < 4u) c_lds[ii * 4 + jr] = e / s;
        }
    }
    __syncthreads();   // c_lds ready (implicit vmcnt(0): round-0 staging landed too)

    f32x16 acc[4][2];   // [jj][b-half]
#pragma unroll
    for (int jj = 0; jj < 4; ++jj) { acc[jj][0] = (f32x16){}; acc[jj][1] = (f32x16){}; }

#pragma unroll
    for (int r = 0; r < IPW; ++r) {
        const int pb = r & 1;
        if (r + 1 < IPW) {   // issue next round: 8 W-DMAs then 4 A-loads
            const float* ws = wsrc + (size_t)(r + 1) * 16384;
            float* wd = wbuf + (pb ^ 1) * 2048;
#pragma unroll
            for (int n = 0; n < 8; ++n)
                GLOAD_LDS16(ws + n * 256, wd + n * 256);
            aP[pb ^ 1][0] = *(const float4*)(alane0 + (r + 1) * 16);
            aP[pb ^ 1][1] = *(const float4*)(alane0 + (r + 1) * 16 + 4);
            aP[pb ^ 1][2] = *(const float4*)(alane1 + (r + 1) * 16);
            aP[pb ^ 1][3] = *(const float4*)(alane1 + (r + 1) * 16 + 4);
        }
        // counted wait: round r's 8 W-DMAs + 4 A-loads done; next round's 12 stay out
        __builtin_amdgcn_sched_barrier(0);
        if (r + 1 < IPW) asm volatile("s_waitcnt vmcnt(12)" ::: "memory");
        else             asm volatile("s_waitcnt vmcnt(0)" ::: "memory");
        __builtin_amdgcn_sched_barrier(0);

        const float* wb = wbuf + pb * 2048;
        short8_t af0, af1;
        af0[0] = f2bf(aP[pb][0].x); af0[1] = f2bf(aP[pb][0].y);
        af0[2] = f2bf(aP[pb][0].z); af0[3] = f2bf(aP[pb][0].w);
        af0[4] = f2bf(aP[pb][1].x); af0[5] = f2bf(aP[pb][1].y);
        af0[6] = f2bf(aP[pb][1].z); af0[7] = f2bf(aP[pb][1].w);
        af1[0] = f2bf(aP[pb][2].x); af1[1] = f2bf(aP[pb][2].y);
        af1[2] = f2bf(aP[pb][2].z); af1[3] = f2bf(aP[pb][2].w);
        af1[4] = f2bf(aP[pb][3].x); af1[5] = f2bf(aP[pb][3].y);
        af1[6] = f2bf(aP[pb][3].z); af1[7] = f2bf(aP[pb][3].w);

#pragma unroll
        for (int jj = 0; jj < 4; ++jj) {
            const float cj = c_lds[(wv * IPW + r) * 4 + jj];
            short8_t bf;
#pragma unroll
            for (int e = 0; e < 8; ++e)
                bf[e] = f2bf(wb[jj * 512 + (g * 8 + e) * 32 + dn] * cj);  // 2-way bank (free)
            acc[jj][0] = __builtin_amdgcn_mfma_f32_32x32x16_bf16(af0, bf, acc[jj][0], 0, 0, 0);
            acc[jj][1] = __builtin_amdgcn_mfma_f32_32x32x16_bf16(af1, bf, acc[jj][1], 0, 0, 0);
        }
    }

    // ---- epilogue: 4 passes (one per jj): 8-wave LDS reduce -> partial ----
    // red region for wave wv = lds + wv*4096 (its own buf0; staging fully consumed)
#pragma unroll
    for (int jj = 0; jj < 4; ++jj) {
        __syncthreads();   // pass p-1 reads done / all waves past main loop
        {
            float* rw = lds + wv * 4096;
#pragma unroll
            for (int reg = 0; reg < 16; ++reg) {
                const int b0 = (reg & 3) + 8 * (reg >> 2) + 4 * g;
                rw[b0 * 32 + dn]        = acc[jj][0][reg];
                rw[(b0 + 32) * 32 + dn] = acc[jj][1][reg];
            }
        }
        __syncthreads();
        {
            const int o = t * 4;   // 512 thr x 4 floats = 2048
            float4 v = {0.f, 0.f, 0.f, 0.f};
#pragma unroll
            for (int w8 = 0; w8 < NWAVE; ++w8) {
                float4 p = *(const float4*)(lds + w8 * 4096 + o);
                v.x += p.x; v.y += p.y; v.z += p.z; v.w += p.w;
            }
            *(float4*)(partial + (size_t)(kc * J_CAP + j0 + jj) * 2048 + o) = v;
        }
    }
}

// ---------------- k2: reduce KCN partials + squash (vectorized) ----------------
// 128 blocks x 256 thr = 32768 threads. tid2 -> row = tid2>>4 (j = row>>6,
// b = row&63), d4 = (tid2>>1)&7, half = tid2&1 (kc half). Each thread sums 16
// kc's as float4, pair-combines via shfl_xor(1), row-squash via shfl 2/4/8.
__global__ __launch_bounds__(256) void caps_reduce_squash_k(const float* __restrict__ partial,
                                                            float* __restrict__ out) {
    const int tid2 = blockIdx.x * 256 + threadIdx.x;
    const int row  = tid2 >> 4;
    const int sub  = tid2 & 15;
    const int d4   = sub >> 1;
    const int half = sub & 1;
    const int j = row >> 6, b = row & 63;

    const float* src = partial + ((size_t)(half * 16) * J_CAP + j) * 2048 + b * 32 + d4 * 4;
    float4 v = {0.f, 0.f, 0.f, 0.f};
#pragma unroll
    for (int kc = 0; kc < 16; ++kc) {
        float4 p = *(const float4*)(src + (size_t)kc * J_CAP * 2048);
        v.x += p.x; v.y += p.y; v.z += p.z; v.w += p.w;
    }
    // combine the two kc-halves (lane pair differs only in `half`)
    v.x += __shfl_xor(v.x, 1); v.y += __shfl_xor(v.y, 1);
    v.z += __shfl_xor(v.z, 1); v.w += __shfl_xor(v.w, 1);

    float sq = v.x * v.x + v.y * v.y + v.z * v.z + v.w * v.w;
#pragma unroll
    for (int m = 2; m <= 8; m <<= 1) sq += __shfl_xor(sq, m);
    // scale = s2 / (1+s2) / sqrt(s2)  (exactly as reference)
    float scale = sq / (1.0f + sq) / sqrtf(sq);
    if (half == 0) {
        float4 o = {v.x * scale, v.y * scale, v.z * scale, v.w * scale};
        *(float4*)(out + (size_t)b * (J_CAP * D_DIM) + j * D_DIM + d4 * 4) = o;
    }
}

extern "C" void kernel_launch(void* const* d_in, const int* in_sizes, int n_in,
                              void* d_out, int out_size, void* d_ws, size_t ws_size,
                              hipStream_t stream) {
    const float* inputs = (const float*)d_in[0];
    const float* W      = (const float*)d_in[1];
    const float* bias   = (const float*)d_in[2];
    float* out = (float*)d_out;

    float* partial = (float*)d_ws;   // 32*32*2048 f32 = 8 MB

    caps_main_k<<<dim3(KCN * 8), dim3(512), 0, stream>>>(inputs, W, bias, partial);
    caps_reduce_squash_k<<<dim3(128), dim3(256), 0, stream>>>(partial, out);
}